// Round 3
// baseline (4337.069 us; speedup 1.0000x reference)
//
#include <hip/hip_runtime.h>
#include <stdint.h>

// Round 2: Round-1 structure; ONLY change is the ball-query dot product, now an
// explicit FMA chain fma(z, fma(y, mul(x))) to match numpy einsum's contracted
// `accum += a[i]*b[i]` inner loop (FMA-dispatched TU, -ffp-contract=fast).
// FPS (validated bit-exact by Output 0 passing) and the srcSq/dstSq/combine
// arithmetic stay contraction-free.

#define NBATCH 8
#define NPTS   8192
#define NCH    128
#define NGROUP 2048
#define NK     24
#define ROWLEN (2 * NCH + 3)   // 259

__device__ __forceinline__ float sq3_nofma(float dx, float dy, float dz) {
#pragma clang fp contract(off)
  return dx * dx + dy * dy + dz * dz;
}

// numpy einsum contracted inner loop: acc = a0*b0; acc = fma(a1,b1,acc); acc = fma(a2,b2,acc)
__device__ __forceinline__ float dot3_fma(float ax, float ay, float az,
                                          float bx, float by, float bz) {
  float acc = __fmul_rn(ax, bx);
  acc = __fmaf_rn(ay, by, acc);
  acc = __fmaf_rn(az, bz, acc);
  return acc;
}

__device__ __forceinline__ float ballquery_sqr(float srcSq, float dstSq, float dot) {
#pragma clang fp contract(off)
  return (srcSq + dstSq) - 2.0f * dot;
}

__global__ __launch_bounds__(1024) void fps_kernel(const float* __restrict__ xyz,
                                                   int* __restrict__ fps_idx) {
  const int b = blockIdx.x;
  const int t = threadIdx.x;
  const float* xb = xyz + (size_t)b * NPTS * 3;

  // thread t owns points n = t + i*1024, i in [0,8)
  float px[8], py[8], pz[8], dist[8];
#pragma unroll
  for (int i = 0; i < 8; ++i) {
    const int n = t + (i << 10);
    px[i] = xb[n * 3 + 0];
    py[i] = xb[n * 3 + 1];
    pz[i] = xb[n * 3 + 2];
    dist[i] = 1e10f;
  }

  __shared__ float s_v[16], s_x[16], s_y[16], s_z[16];
  __shared__ int s_i[16];
  __shared__ float s_rx, s_ry, s_rz;
  __shared__ int s_ri;

  float cx = xb[0], cy = xb[1], cz = xb[2];   // centroid 0 = point 0
  if (t == 0) fps_idx[b * NGROUP + 0] = 0;

  for (int s = 1; s < NGROUP; ++s) {
    float bestv = -1.0f;
    int besti = 0x7fffffff;
    float bx = 0.f, by = 0.f, bz = 0.f;
#pragma unroll
    for (int i = 0; i < 8; ++i) {
      float dx, dy, dz, dd;
      {
#pragma clang fp contract(off)
        dx = px[i] - cx;
        dy = py[i] - cy;
        dz = pz[i] - cz;
        dd = dx * dx + dy * dy + dz * dz;   // ((x+y)+z), never fused
      }
      const float nd = fminf(dist[i], dd);
      dist[i] = nd;
      // indices ascend with i, so strict > keeps the first (smallest) index on ties
      if (nd > bestv) { bestv = nd; besti = t + (i << 10); bx = px[i]; by = py[i]; bz = pz[i]; }
    }
    const int myi = besti;
    // in-wave butterfly argmax on (value desc, index asc)
#pragma unroll
    for (int off = 32; off >= 1; off >>= 1) {
      const float ov = __shfl_xor(bestv, off, 64);
      const int oi = __shfl_xor(besti, off, 64);
      if (ov > bestv || (ov == bestv && oi < besti)) { bestv = ov; besti = oi; }
    }
    const int w = t >> 6;
    if (besti == myi) { s_x[w] = bx; s_y[w] = by; s_z[w] = bz; }  // unique winning lane per wave
    if ((t & 63) == 0) { s_v[w] = bestv; s_i[w] = besti; }
    __syncthreads();
    if (t < 64) {
      float v, x, y, z; int idx;
      if (t < 16) { v = s_v[t]; idx = s_i[t]; x = s_x[t]; y = s_y[t]; z = s_z[t]; }
      else        { v = -2.0f;  idx = 0x7fffffff; x = 0.f; y = 0.f; z = 0.f; }
#pragma unroll
      for (int off = 8; off >= 1; off >>= 1) {
        const float ov = __shfl_xor(v, off, 64);
        const int oi = __shfl_xor(idx, off, 64);
        const float ox = __shfl_xor(x, off, 64);
        const float oy = __shfl_xor(y, off, 64);
        const float oz = __shfl_xor(z, off, 64);
        if (ov > v || (ov == v && oi < idx)) { v = ov; idx = oi; x = ox; y = oy; z = oz; }
      }
      if (t == 0) { s_ri = idx; s_rx = x; s_ry = y; s_rz = z; }
    }
    __syncthreads();
    cx = s_rx; cy = s_ry; cz = s_rz;
    if (t == 0) fps_idx[b * NGROUP + s] = s_ri;
  }
}

__global__ __launch_bounds__(256) void group_kernel(const float* __restrict__ xyz,
                                                    const float* __restrict__ points,
                                                    const int* __restrict__ fps_idx,
                                                    float* __restrict__ out) {
  const int gb = blockIdx.x;        // b*NGROUP + g
  const int b = gb >> 11;
  const int tid = threadIdx.x;
  const float* xb = xyz + (size_t)b * NPTS * 3;
  const float* pb = points + (size_t)b * NPTS * NCH;

  __shared__ int s_idx[NK];

  const int a_idx = fps_idx[gb];
  const float cx = xb[a_idx * 3 + 0];
  const float cy = xb[a_idx * 3 + 1];
  const float cz = xb[a_idx * 3 + 2];
  const float srcSq = sq3_nofma(cx, cy, cz);
  const float R2 = (float)(0.2 * 0.2);

  if (tid < 64) {
    int cnt = 0;
    int first = 0;
    for (int chunk = 0; chunk < NPTS / 64; ++chunk) {
      const int n = (chunk << 6) + tid;
      const float x = xb[n * 3 + 0];
      const float y = xb[n * 3 + 1];
      const float z = xb[n * 3 + 2];
      const float dstSq = sq3_nofma(x, y, z);
      const float dot = dot3_fma(cx, cy, cz, x, y, z);
      // (srcSq + dstSq) - 2*dot  — replication of _square_distance (np einsum dot = fma chain)
      const float sqr = ballquery_sqr(srcSq, dstSq, dot);
      const bool ok = !(sqr > R2);
      const unsigned long long mask = __ballot(ok);
      if (cnt == 0 && mask != 0ull) first = (chunk << 6) + (int)__builtin_ctzll(mask);
      const int prefix = (int)__popcll(mask & ((1ull << tid) - 1ull));
      const int pos = cnt + prefix;
      if (ok && pos < NK) s_idx[pos] = n;
      cnt += (int)__popcll(mask);
      if (cnt >= NK) break;
    }
    if (tid >= cnt && tid < NK) s_idx[tid] = first;  // pad with first in-radius index
  }
  __syncthreads();

  // output 0: new_xyz (exact copy of the centroid row)
  if (tid == 0) {
    float* onx = out + (size_t)gb * 3;
    onx[0] = cx; onx[1] = cy; onx[2] = cz;
  }

  // output 1: new_points rows — [points[idx](128) | xyz[idx](3) | points[anchor](128)]
  float* op = out + (size_t)NBATCH * NGROUP * 3 + (size_t)gb * (NK * ROWLEN);
  const float* anchor = pb + (size_t)a_idx * NCH;
  for (int e = tid; e < NK * ROWLEN; e += 256) {
    const int k = e / ROWLEN;
    const int c = e - k * ROWLEN;
    const int si = s_idx[k];
    float v;
    if (c < NCH)            v = pb[(size_t)si * NCH + c];
    else if (c < NCH + 3)   v = xb[si * 3 + (c - NCH)];
    else                    v = anchor[c - (NCH + 3)];
    op[e] = v;
  }
}

extern "C" void kernel_launch(void* const* d_in, const int* in_sizes, int n_in,
                              void* d_out, int out_size, void* d_ws, size_t ws_size,
                              hipStream_t stream) {
  const float* xyz = (const float*)d_in[0];
  const float* points = (const float*)d_in[1];
  float* out = (float*)d_out;
  int* fps_idx = (int*)d_ws;  // 8*2048 ints

  fps_kernel<<<dim3(NBATCH), dim3(1024), 0, stream>>>(xyz, fps_idx);
  group_kernel<<<dim3(NBATCH * NGROUP), dim3(256), 0, stream>>>(xyz, points, fps_idx, out);
}

// Round 4
// 2875.318 us; speedup vs baseline: 1.5084x; 1.5084x over previous
//
#include <hip/hip_runtime.h>
#include <stdint.h>

// Round 3: FPS critical-path rewrite (validated arithmetic untouched).
//  - Thread t owns CONTIGUOUS points [8t, 8t+8) so lane order == index order and
//    ballot+ctz implements np.argmax first-index tie-break.
//  - Wave argmax: DPP max (row_shr 1/2/4/8, bcast15, bcast31) + readlane(63), then
//    ballot(lv==wmax)+ctz -> winner lane, readlane -> winner index. ~50 cyc vs
//    ~400+ for the old ds_swizzle butterfly.
//  - Phase 2 done redundantly by ALL waves (read 16 partials, row-DPP max,
//    ballot+readlane) -> no s_ri LDS round-trip, no wave-0 serialization.
//  - Centroid coords for next iter: readfirstlane(idx) -> uniform scalar loads (L2).
//  - group_kernel: ball query scans 2 points/lane (128/chunk, float2 loads);
//    per-point formulas bit-identical to Round 2, ordered compaction extended to
//    the interleaved (lane-major, 2/lane) layout.

#define NBATCH 8
#define NPTS   8192
#define NCH    128
#define NGROUP 2048
#define NK     24
#define ROWLEN (2 * NCH + 3)   // 259

__device__ __forceinline__ float sq3_nofma(float dx, float dy, float dz) {
#pragma clang fp contract(off)
  return dx * dx + dy * dy + dz * dz;
}

// numpy einsum contracted inner loop: acc = a0*b0; acc = fma(a1,b1,acc); acc = fma(a2,b2,acc)
__device__ __forceinline__ float dot3_fma(float ax, float ay, float az,
                                          float bx, float by, float bz) {
  float acc = __fmul_rn(ax, bx);
  acc = __fmaf_rn(ay, by, acc);
  acc = __fmaf_rn(az, bz, acc);
  return acc;
}

__device__ __forceinline__ float ballquery_sqr(float srcSq, float dstSq, float dot) {
#pragma clang fp contract(off)
  return (srcSq + dstSq) - 2.0f * dot;
}

template <int CTRL>
__device__ __forceinline__ float maxdpp(float v) {
  int s = __builtin_amdgcn_update_dpp(__builtin_bit_cast(int, v),
                                      __builtin_bit_cast(int, v),
                                      CTRL, 0xF, 0xF, false);
  return fmaxf(v, __builtin_bit_cast(float, s));
}

__device__ __forceinline__ float readlane_f(float v, int lane) {
  return __builtin_bit_cast(float,
      __builtin_amdgcn_readlane(__builtin_bit_cast(int, v), lane));
}

__global__ __launch_bounds__(1024) void fps_kernel(const float* __restrict__ xyz,
                                                   int* __restrict__ fps_idx) {
  const int b = blockIdx.x;
  const int t = threadIdx.x;
  const int lane = t & 63;
  const int w = t >> 6;
  const float* xb = xyz + (size_t)b * NPTS * 3;

  // thread t owns points [8t, 8t+8)  (contiguous -> lane order == index order)
  const int base = t << 3;
  float px[8], py[8], pz[8], dist[8];
#pragma unroll
  for (int i = 0; i < 8; ++i) {
    const int n = base + i;
    px[i] = xb[n * 3 + 0];
    py[i] = xb[n * 3 + 1];
    pz[i] = xb[n * 3 + 2];
    dist[i] = 1e10f;
  }

  __shared__ float s_v[16];
  __shared__ int s_i[16];

  float cx = xb[0], cy = xb[1], cz = xb[2];   // centroid 0 = point 0
  if (t == 0) fps_idx[b * NGROUP + 0] = 0;

  for (int s = 1; s < NGROUP; ++s) {
    // ---- phase 1: min-update + local argmax (exact, contraction-free) ----
    float lv = -1.0f;
    int li = 0;
#pragma unroll
    for (int i = 0; i < 8; ++i) {
      float dx, dy, dz, dd;
      {
#pragma clang fp contract(off)
        dx = px[i] - cx;
        dy = py[i] - cy;
        dz = pz[i] - cz;
        dd = dx * dx + dy * dy + dz * dz;   // ((x+y)+z), never fused
      }
      const float nd = fminf(dist[i], dd);
      dist[i] = nd;
      if (nd > lv) { lv = nd; li = base + i; }   // strict > : first index wins
    }

    // ---- wave argmax via DPP (value max, then ballot for first index) ----
    float v = lv;
    v = maxdpp<0x111>(v);   // row_shr:1
    v = maxdpp<0x112>(v);   // row_shr:2
    v = maxdpp<0x114>(v);   // row_shr:4
    v = maxdpp<0x118>(v);   // row_shr:8
    v = maxdpp<0x142>(v);   // row_bcast15
    v = maxdpp<0x143>(v);   // row_bcast31
    const float wmax = readlane_f(v, 63);
    const unsigned long long m = __ballot(lv == wmax);
    const int wl = (int)__builtin_ctzll(m);            // lowest lane = lowest index
    const int wli = __builtin_amdgcn_readlane(li, wl);
    if (lane == 0) { s_v[w] = wmax; s_i[w] = wli; }
    __syncthreads();

    // ---- phase 2: every wave reduces the 16 partials (no extra round-trip) ----
    float pv = (lane < 16) ? s_v[lane] : -1.0f;
    int pi = (lane < 16) ? s_i[lane] : 0;
    float r = pv;
    r = maxdpp<0x111>(r);
    r = maxdpp<0x112>(r);
    r = maxdpp<0x114>(r);
    r = maxdpp<0x118>(r);
    const float bmax = readlane_f(r, 15);
    const unsigned long long m2 = __ballot(pv == bmax);
    const int wwin = (int)__builtin_ctzll(m2);         // lowest wave = lowest index
    const int bi = __builtin_amdgcn_readlane(pi, wwin);

    if (t == 0) fps_idx[b * NGROUP + s] = bi;

    // next centroid coords: uniform scalar loads
    const int ci = __builtin_amdgcn_readfirstlane(bi);
    cx = xb[ci * 3 + 0];
    cy = xb[ci * 3 + 1];
    cz = xb[ci * 3 + 2];
    __syncthreads();   // protect s_v/s_i reuse next iteration
  }
}

__global__ __launch_bounds__(256) void group_kernel(const float* __restrict__ xyz,
                                                    const float* __restrict__ points,
                                                    const int* __restrict__ fps_idx,
                                                    float* __restrict__ out) {
  const int gb = blockIdx.x;        // b*NGROUP + g
  const int b = gb >> 11;
  const int tid = threadIdx.x;
  const float* xb = xyz + (size_t)b * NPTS * 3;
  const float* pb = points + (size_t)b * NPTS * NCH;

  __shared__ int s_idx[NK];

  const int a_idx = fps_idx[gb];
  const float cx = xb[a_idx * 3 + 0];
  const float cy = xb[a_idx * 3 + 1];
  const float cz = xb[a_idx * 3 + 2];
  const float srcSq = sq3_nofma(cx, cy, cz);
  const float R2 = (float)(0.2 * 0.2);

  if (tid < 64) {
    int cnt = 0;
    int first = 0;
    const unsigned long long below = ((unsigned long long)1 << tid) - 1ull;
    for (int chunk = 0; chunk < NPTS / 128; ++chunk) {
      const int n0 = (chunk << 7) + (tid << 1);        // 2 points per lane
      const float* p = xb + (size_t)n0 * 3;            // 24B-aligned
      const float2 A = *(const float2*)(p + 0);        // x0 y0
      const float2 Bv = *(const float2*)(p + 2);       // z0 x1
      const float2 C = *(const float2*)(p + 4);        // y1 z1
      const float x0 = A.x, y0 = A.y, z0 = Bv.x;
      const float x1 = Bv.y, y1 = C.x, z1 = C.y;

      const float sqr0 = ballquery_sqr(srcSq, sq3_nofma(x0, y0, z0),
                                       dot3_fma(cx, cy, cz, x0, y0, z0));
      const float sqr1 = ballquery_sqr(srcSq, sq3_nofma(x1, y1, z1),
                                       dot3_fma(cx, cy, cz, x1, y1, z1));
      const bool ok0 = !(sqr0 > R2);
      const bool ok1 = !(sqr1 > R2);
      const unsigned long long m0 = __ballot(ok0);
      const unsigned long long m1 = __ballot(ok1);
      if (cnt == 0 && (m0 | m1)) {
        const int f0 = m0 ? (int)__builtin_ctzll(m0) : 64;
        const int f1 = m1 ? (int)__builtin_ctzll(m1) : 64;
        first = (f0 <= f1) ? ((chunk << 7) + 2 * f0) : ((chunk << 7) + 2 * f1 + 1);
      }
      const int p0 = cnt + (int)__popcll(m0 & below) + (int)__popcll(m1 & below);
      const int p1 = p0 + (ok0 ? 1 : 0);
      if (ok0 && p0 < NK) s_idx[p0] = n0;
      if (ok1 && p1 < NK) s_idx[p1] = n0 + 1;
      cnt += (int)__popcll(m0) + (int)__popcll(m1);
      if (cnt >= NK) break;
    }
    if (tid >= cnt && tid < NK) s_idx[tid] = first;  // pad with first in-radius index
  }
  __syncthreads();

  // output 0: new_xyz (exact copy of the centroid row)
  if (tid == 0) {
    float* onx = out + (size_t)gb * 3;
    onx[0] = cx; onx[1] = cy; onx[2] = cz;
  }

  // output 1: new_points rows — [points[idx](128) | xyz[idx](3) | points[anchor](128)]
  float* op = out + (size_t)NBATCH * NGROUP * 3 + (size_t)gb * (NK * ROWLEN);
  const float* anchor = pb + (size_t)a_idx * NCH;
  for (int e = tid; e < NK * ROWLEN; e += 256) {
    const int k = e / ROWLEN;
    const int c = e - k * ROWLEN;
    const int si = s_idx[k];
    float v;
    if (c < NCH)            v = pb[(size_t)si * NCH + c];
    else if (c < NCH + 3)   v = xb[si * 3 + (c - NCH)];
    else                    v = anchor[c - (NCH + 3)];
    op[e] = v;
  }
}

extern "C" void kernel_launch(void* const* d_in, const int* in_sizes, int n_in,
                              void* d_out, int out_size, void* d_ws, size_t ws_size,
                              hipStream_t stream) {
  const float* xyz = (const float*)d_in[0];
  const float* points = (const float*)d_in[1];
  float* out = (float*)d_out;
  int* fps_idx = (int*)d_ws;  // 8*2048 ints

  fps_kernel<<<dim3(NBATCH), dim3(1024), 0, stream>>>(xyz, fps_idx);
  group_kernel<<<dim3(NBATCH * NGROUP), dim3(256), 0, stream>>>(xyz, points, fps_idx, out);
}